// Round 12
// baseline (192.688 us; speedup 1.0000x reference)
//
#include <hip/hip_runtime.h>

#define N_ROWS 32768
#define D_IN 320
#define CB 16
#define N_BOOKS 8192

typedef __attribute__((ext_vector_type(8))) short bf16x8;
typedef __attribute__((ext_vector_type(4))) float f32x4;
#define MFMA __builtin_amdgcn_mfma_f32_16x16x32_bf16
#define AS1 __attribute__((address_space(1)))
#define AS3 __attribute__((address_space(3)))

__device__ __forceinline__ unsigned short bf16rn(float f) {
  unsigned u = __float_as_uint(f);
  u += 0x7fffu + ((u >> 16) & 1u);
  return (unsigned short)(u >> 16);
}
__device__ __forceinline__ float bf16tof(unsigned short h) {
  return __uint_as_float(((unsigned)h) << 16);
}
// async global->LDS, 16B per lane; lds ptr must be wave-uniform base
__device__ __forceinline__ void gload_lds16(const short* g, short* l) {
  __builtin_amdgcn_global_load_lds((const AS1 unsigned int*)g, (AS3 unsigned int*)l, 16, 0, 0);
}

// ---------------- Kernel 1 (fused): proj (blocks 0..511) + codebook prep (512..543) -------
// prep: 2-SPLIT bfrag[bt][split][lane][8]; B1=[c1|c1], B2=[c2|c2]; tile = 1024 shorts.
// nh = -0.5||c||^2 (fp64). Zeroes flagged-row counter.
// proj: targets = X @ W^T via bf16 3-split MFMA, f32 chained accumulators.
__global__ __launch_bounds__(256, 2) void proj_prep_kernel(
    const float* __restrict__ x, const float* __restrict__ w, short* __restrict__ tsplit,
    const float* __restrict__ cbk, short* __restrict__ bfrag, float* __restrict__ nh_g,
    int* __restrict__ ctr) {
  __shared__ __align__(16) short wfrag[3][10][64][8];  // 30720 B
  __shared__ __align__(16) float xs[2][64 * 36];       // 18432 B
  const int tid = threadIdx.x;

  if (blockIdx.x >= 512) {  // ---- prep branch (no LDS, no syncthreads) ----
    const int bid = blockIdx.x - 512;
    if (bid == 0 && tid == 0) *ctr = 0;
    const int j = bid * 256 + tid;
    const float4* src = (const float4*)(cbk + (size_t)j * CB);
    float4 a = src[0], b = src[1], c = src[2], d = src[3];
    float ce[16] = {a.x, a.y, a.z, a.w, b.x, b.y, b.z, b.w,
                    c.x, c.y, c.z, c.w, d.x, d.y, d.z, d.w};
    short c1[16], c2[16];
    double s = 0.0;
#pragma unroll
    for (int i = 0; i < 16; i++) {
      s += (double)ce[i] * (double)ce[i];
      unsigned short x1 = bf16rn(ce[i]);
      float r1 = ce[i] - bf16tof(x1);
      unsigned short x2 = bf16rn(r1);
      c1[i] = (short)x1; c2[i] = (short)x2;
    }
    nh_g[j] = (float)(-0.5 * s);
    bf16x8 lo1, hi1, lo2, hi2;
#pragma unroll
    for (int i = 0; i < 8; i++) {
      lo1[i] = c1[i]; hi1[i] = c1[i + 8];
      lo2[i] = c2[i]; hi2[i] = c2[i + 8];
    }
    const int bt = j >> 4, n = j & 15;
    short* base = bfrag + (size_t)bt * 1024;
    *(bf16x8*)(base + (0 * 16 + n) * 8) = lo1;
    *(bf16x8*)(base + (1 * 16 + n) * 8) = hi1;
    *(bf16x8*)(base + (2 * 16 + n) * 8) = lo1;
    *(bf16x8*)(base + (3 * 16 + n) * 8) = hi1;
    *(bf16x8*)(base + 512 + (0 * 16 + n) * 8) = lo2;
    *(bf16x8*)(base + 512 + (1 * 16 + n) * 8) = hi2;
    *(bf16x8*)(base + 512 + (2 * 16 + n) * 8) = lo2;
    *(bf16x8*)(base + 512 + (3 * 16 + n) * 8) = hi2;
    return;
  }

  // ---- proj branch ----
  const int lane = tid & 63;
  const int wv = tid >> 6;

  for (int i = tid; i < D_IN * CB; i += 256) {
    int d = i >> 4, o = i & 15;
    float f = w[o * D_IN + d];
    unsigned short h1 = bf16rn(f);
    float r1 = f - bf16tof(h1);
    unsigned short h2 = bf16rn(r1);
    float r2 = r1 - bf16tof(h2);
    unsigned short h3 = bf16rn(r2);
    int c = d >> 5, qq = (d >> 3) & 3, pos = d & 7;
    int ln = qq * 16 + o;
    wfrag[0][c][ln][pos] = (short)h1;
    wfrag[1][c][ln][pos] = (short)h2;
    wfrag[2][c][ln][pos] = (short)h3;
  }

  const float* xblk = x + (size_t)blockIdx.x * 64 * D_IN;
  {
    int row = tid >> 2, k0 = (tid & 3) * 8;
    float4 v0 = *(const float4*)(xblk + row * D_IN + k0);
    float4 v1 = *(const float4*)(xblk + row * D_IN + k0 + 4);
    *(float4*)&xs[0][row * 36 + k0] = v0;
    *(float4*)&xs[0][row * 36 + k0 + 4] = v1;
  }
  __syncthreads();

  const int m = lane & 15, q = lane >> 4;
  f32x4 g1 = {0.f, 0.f, 0.f, 0.f}, g2 = {0.f, 0.f, 0.f, 0.f}, g3 = {0.f, 0.f, 0.f, 0.f};
  for (int c = 0; c < 10; c++) {
    const int buf = c & 1;
    if (c < 9) {
      int row = tid >> 2, k0 = (tid & 3) * 8;
      float4 v0 = *(const float4*)(xblk + row * D_IN + (c + 1) * 32 + k0);
      float4 v1 = *(const float4*)(xblk + row * D_IN + (c + 1) * 32 + k0 + 4);
      *(float4*)&xs[buf ^ 1][row * 36 + k0] = v0;
      *(float4*)&xs[buf ^ 1][row * 36 + k0 + 4] = v1;
    }
    const float* xp = &xs[buf][(wv * 16 + m) * 36 + q * 8];
    float4 xa = *(const float4*)xp;
    float4 xb = *(const float4*)(xp + 4);
    float xe[8] = {xa.x, xa.y, xa.z, xa.w, xb.x, xb.y, xb.z, xb.w};
    bf16x8 a1, a2, a3;
#pragma unroll
    for (int j = 0; j < 8; j++) {
      unsigned short h1 = bf16rn(xe[j]);
      float r1 = xe[j] - bf16tof(h1);
      unsigned short h2 = bf16rn(r1);
      float r2 = r1 - bf16tof(h2);
      unsigned short h3 = bf16rn(r2);
      a1[j] = (short)h1; a2[j] = (short)h2; a3[j] = (short)h3;
    }
    bf16x8 b1 = *(const bf16x8*)wfrag[0][c][lane];
    bf16x8 b2 = *(const bf16x8*)wfrag[1][c][lane];
    bf16x8 b3 = *(const bf16x8*)wfrag[2][c][lane];
    g1 = MFMA(a1, b1, g1, 0, 0, 0);
    g2 = MFMA(a2, b1, g2, 0, 0, 0);
    g2 = MFMA(a1, b2, g2, 0, 0, 0);
    g3 = MFMA(a3, b1, g3, 0, 0, 0);
    g3 = MFMA(a1, b3, g3, 0, 0, 0);
    g3 = MFMA(a2, b2, g3, 0, 0, 0);
    __syncthreads();
  }

  float* tl = (float*)xs;  // 64 rows x stride 17
#pragma unroll
  for (int r = 0; r < 4; r++) {
    double t = (double)g1[r] + ((double)g2[r] + (double)g3[r]);
    tl[(wv * 16 + q * 4 + r) * 17 + m] = (float)t;
  }
  __syncthreads();
  {
    int row_l = tid >> 2, p = tid & 3;
    short h1[4], h2[4], h3[4];
#pragma unroll
    for (int i = 0; i < 4; i++) {
      float f = tl[row_l * 17 + p * 4 + i];
      unsigned short a = bf16rn(f);
      float r1 = f - bf16tof(a);
      unsigned short b = bf16rn(r1);
      float r2 = r1 - bf16tof(b);
      unsigned short cc = bf16rn(r2);
      h1[i] = (short)a; h2[i] = (short)b; h3[i] = (short)cc;
    }
    size_t base = (size_t)(blockIdx.x * 64 + row_l) * 48;
    *(short4*)(tsplit + base + p * 4) = make_short4(h1[0], h1[1], h1[2], h1[3]);
    *(short4*)(tsplit + base + 16 + p * 4) = make_short4(h2[0], h2[1], h2[2], h2[3]);
    *(short4*)(tsplit + base + 32 + p * 4) = make_short4(h3[0], h3[1], h3[2], h3[3]);
  }
}

// ---------------- Kernel 2: per-wave private 4-buf ring, depth-3 vmcnt, NO barriers -------
// R12: R8's best compute geometry (256 thr, 4 rt/wave, 2-split, 6-bit tagged top-2) on a
// barrier-free schedule. Each wave owns a 4 x 2KB LDS ring: stage tile t+3 (2 gload_lds),
// s_waitcnt vmcnt(6) (tiles t+1..t+3 in flight = ~750cyc cover vs ~250cyc L2 latency —
// fixes R7's depth-1 failure), compute tile t. Zero __syncthreads after prologue: waves
// fully decoupled (no convoy — the suspected cause of the 67-70us plateau at 29-35% occ).
// MFMAs clustered under s_setprio(1) (T5: waves at different phases -> arbitration helps).
// LDS 4w x 8KB + 4KB nh = 36864 B -> 4 blk/CU; grid 1024 = 4/CU.
#define SC_H 8

__global__ __launch_bounds__(256, 2) void score_kernel(const short* __restrict__ tsplit,
                                                       const short* __restrict__ bfrag,
                                                       const float* __restrict__ nh_g,
                                                       float4* __restrict__ cand) {
  __shared__ __align__(16) short ldsb[4][4][1024];  // [wave][ring slot][2KB tile]
  __shared__ float ldsnh[1024];                     // 4 KB
  const int tid = threadIdx.x;
  const int lane = tid & 63;
  const int wv = tid >> 6;
  const int m = lane & 15, q = lane >> 4;
  const int rb = blockIdx.x & 127;
  const int h = blockIdx.x >> 7;  // 0..7
  const int rowbase = rb * 256;

  // A-frags from prepacked tsplit: A12 = [t1|t2]; wave covers 64 rows
  bf16x8 A12[4];
#pragma unroll
  for (int rt = 0; rt < 4; rt++) {
    int row = rowbase + wv * 64 + rt * 16 + m;
    A12[rt] = *(const bf16x8*)(tsplit + (size_t)row * 48 + q * 8);
  }
  for (int i = tid; i < 1024; i += 256) ldsnh[i] = nh_g[h * 1024 + i];

  const short* gw = bfrag + (size_t)h * 65536 + lane * 8;  // this eighth, lane offset baked
  short* mybuf = &ldsb[wv][0][0];
  // prologue: stage tiles 0,1,2 into ring slots 0,1,2
#pragma unroll
  for (int t = 0; t < 3; t++) {
    gload_lds16(gw + t * 1024, mybuf + t * 1024);
    gload_lds16(gw + t * 1024 + 512, mybuf + t * 1024 + 512);
  }

  const unsigned qmask = 0xFFFFFFC0u;
  float s1[4][4], s2[4][4];
#pragma unroll
  for (int rt = 0; rt < 4; rt++)
#pragma unroll
    for (int r = 0; r < 4; r++) { s1[rt][r] = -3.4e38f; s2[rt][r] = -3.4e38f; }

  __syncthreads();  // nh visible; drains prologue stages (one-time cost); only barrier

  for (int t = 0; t < 64; t++) {
    if (t < 61) {  // stage t+3; tiles t+1..t+3 stay in flight across the wait
      const short* gs = gw + (t + 3) * 1024;
      short* ld = mybuf + ((t + 3) & 3) * 1024;
      gload_lds16(gs, ld);
      gload_lds16(gs + 512, ld + 512);
      asm volatile("s_waitcnt vmcnt(6)" ::: "memory");  // tile t's 2 loads complete
    } else if (t == 61) {
      asm volatile("s_waitcnt vmcnt(4)" ::: "memory");
    } else if (t == 62) {
      asm volatile("s_waitcnt vmcnt(2)" ::: "memory");
    } else {
      asm volatile("s_waitcnt vmcnt(0)" ::: "memory");
    }
    const short* bp = mybuf + (t & 3) * 1024;
    bf16x8 b1 = *(const bf16x8*)(bp + lane * 8);
    bf16x8 b2 = *(const bf16x8*)(bp + 512 + lane * 8);
    float nh0 = ldsnh[t * 16 + m];
    f32x4 ci = {nh0, nh0, nh0, nh0};
    // clustered MFMAs: 4 independent 2-chains (ILP), prio-boosted
    __builtin_amdgcn_s_setprio(1);
    f32x4 a0 = MFMA(A12[0], b1, ci, 0, 0, 0);
    f32x4 a1 = MFMA(A12[1], b1, ci, 0, 0, 0);
    f32x4 a2 = MFMA(A12[2], b1, ci, 0, 0, 0);
    f32x4 a3 = MFMA(A12[3], b1, ci, 0, 0, 0);
    a0 = MFMA(A12[0], b2, a0, 0, 0, 0);
    a1 = MFMA(A12[1], b2, a1, 0, 0, 0);
    a2 = MFMA(A12[2], b2, a2, 0, 0, 0);
    a3 = MFMA(A12[3], b2, a3, 0, 0, 0);
    __builtin_amdgcn_s_setprio(0);
    const unsigned tagv = (unsigned)(63 - t);  // prefer low tile on quantized ties
#pragma unroll
    for (int r = 0; r < 4; r++) {
      float vq0 = __uint_as_float((__float_as_uint(a0[r]) & qmask) | tagv);
      s2[0][r] = __builtin_amdgcn_fmed3f(vq0, s1[0][r], s2[0][r]);
      s1[0][r] = fmaxf(s1[0][r], vq0);
      float vq1 = __uint_as_float((__float_as_uint(a1[r]) & qmask) | tagv);
      s2[1][r] = __builtin_amdgcn_fmed3f(vq1, s1[1][r], s2[1][r]);
      s1[1][r] = fmaxf(s1[1][r], vq1);
      float vq2 = __uint_as_float((__float_as_uint(a2[r]) & qmask) | tagv);
      s2[2][r] = __builtin_amdgcn_fmed3f(vq2, s1[2][r], s2[2][r]);
      s1[2][r] = fmaxf(s1[2][r], vq2);
      float vq3 = __uint_as_float((__float_as_uint(a3[r]) & qmask) | tagv);
      s2[3][r] = __builtin_amdgcn_fmed3f(vq3, s1[3][r], s2[3][r]);
      s1[3][r] = fmaxf(s1[3][r], vq3);
    }
  }

  // cross-lane top-2 merge over 16 column-lanes; index recovered from tag + ballot
#pragma unroll
  for (int rt = 0; rt < 4; rt++)
#pragma unroll
    for (int r = 0; r < 4; r++) {
      float s1v = s1[rt][r], s2v = s2[rt][r];
      const float ps1 = s1v;  // pre-merge value: identifies the owner lane
#pragma unroll
      for (int msk = 1; msk <= 8; msk <<= 1) {
        float o1 = __shfl_xor(s1v, msk);
        float o2 = __shfl_xor(s2v, msk);
        s2v = __builtin_amdgcn_fmed3f(s1v, o1, fmaxf(s2v, o2));
        s1v = fmaxf(s1v, o1);
      }
      unsigned long long bal = __ballot(ps1 == s1v);
      unsigned grp = (unsigned)((bal >> (q * 16)) & 0xFFFFull);
      int mwin = __builtin_ctz(grp | 0x10000u);  // grp!=0 guaranteed; | is safety
      int btwin = 63 - (int)(__float_as_uint(s1v) & 63u);
      int col = h * 1024 + btwin * 16 + mwin;
      if (m == 0) {
        int row = rowbase + wv * 64 + rt * 16 + q * 4 + r;
        cand[(size_t)h * N_ROWS + row] = make_float4(s1v, s2v, __int_as_float(col), 0.f);
      }
    }
}

// ---------------- Kernel 3a: merge eighths, flag near-ties into compacted list ------------
// eps 1e-3 covers: 2-split error (~2e-4) + mantissa quantization (<=2.4e-4).
#define MARGIN_EPS 1.0e-3f

__global__ __launch_bounds__(256) void merge_flag_kernel(const float4* __restrict__ cand,
                                                         int* __restrict__ out,
                                                         int* __restrict__ list,
                                                         int* __restrict__ ctr) {
  const int r = blockIdx.x * 256 + threadIdx.x;
  float S1 = -3.4e38f, S2 = -3.4e38f;
  int I = 0;
#pragma unroll
  for (int h = 0; h < SC_H; h++) {  // ascending + strict '>' => min index on ties
    float4 v = cand[(size_t)h * N_ROWS + r];
    if (v.x > S1) {
      S2 = fmaxf(S1, v.y); S1 = v.x; I = __float_as_int(v.z);
    } else {
      S2 = fmaxf(S2, v.x);
    }
  }
  out[r] = I;
  if (S1 - S2 < MARGIN_EPS) {
    int slot = atomicAdd(ctr, 1);  // device-scope by default: safe across XCDs
    list[slot] = r;
  }
}

// ---------------- Kernel 3b: exact fp64 rescore, one block per flagged row ----------------
__global__ __launch_bounds__(256) void rescore_kernel(const int* __restrict__ list,
                                                      const int* __restrict__ ctr,
                                                      const float* __restrict__ x,
                                                      const float* __restrict__ w,
                                                      const float* __restrict__ codebook,
                                                      int* __restrict__ out) {
  __shared__ double ps[16][17];
  __shared__ double tsh[16];
  __shared__ double rs[256];
  __shared__ int ri[256];
  const int tid = threadIdx.x;
  const int total = ctr[0];

  for (int it = blockIdx.x; it < total; it += gridDim.x) {
    const int row = list[it];
    {  // exact fp64 t = x_row . W^T
      int o = tid & 15, c = tid >> 4;
      double p = 0.0;
      for (int k = 0; k < 20; k++) {
        int d = c * 20 + k;
        p = fma((double)x[(size_t)row * D_IN + d], (double)w[o * D_IN + d], p);
      }
      ps[c][o] = p;
    }
    __syncthreads();
    if (tid < 16) {
      double t = 0.0;
      for (int c = 0; c < 16; c++) t += ps[c][tid];
      tsh[tid] = t;
    }
    __syncthreads();
    double t[16];
#pragma unroll
    for (int i = 0; i < 16; i++) t[i] = tsh[i];
    double bs = -1.0e300;
    int bi = 0;
    for (int j = tid; j < N_BOOKS; j += 256) {
      const float* cp = codebook + (size_t)j * CB;
      double dot = 0.0, cc = 0.0;
#pragma unroll
      for (int i = 0; i < 16; i++) {
        double cv = (double)cp[i];
        dot = fma(t[i], cv, dot);
        cc = fma(cv, cv, cc);
      }
      double mv = dot - 0.5 * cc;
      if (mv > bs) { bs = mv; bi = j; }  // ascending j: first wins
    }
    rs[tid] = bs; ri[tid] = bi;
    __syncthreads();
    for (int s = 128; s > 0; s >>= 1) {
      if (tid < s) {
        double os = rs[tid + s]; int oi = ri[tid + s];
        if (os > rs[tid] || (os == rs[tid] && oi < ri[tid])) { rs[tid] = os; ri[tid] = oi; }
      }
      __syncthreads();
    }
    if (tid == 0) out[row] = ri[0];
    __syncthreads();  // protect ps/rs reuse on next list item
  }
}

extern "C" void kernel_launch(void* const* d_in, const int* in_sizes, int n_in,
                              void* d_out, int out_size, void* d_ws, size_t ws_size,
                              hipStream_t stream) {
  (void)in_sizes; (void)n_in; (void)out_size; (void)ws_size;
  const float* x = (const float*)d_in[0];
  // d_in[1] = mask_time_indices: all-ones -> flatten; unused
  const float* w = (const float*)d_in[2];
  const float* codebook = (const float*)d_in[3];

  char* ws = (char*)d_ws;
  short* tsplit = (short*)(ws);              // 3 MB   (32768 x 48 shorts)
  short* bfrag = (short*)(ws + (3 << 20));   // 1 MB   (512 bt x 1024 shorts)
  float* nh_g = (float*)(ws + (4 << 20));    // 32 KB
  int* list = (int*)(ws + 4231168);          // 128 KB flagged-row list (4KB pad before)
  int* ctr = (int*)(ws + 4362240);           // 4 B    flagged-row count
  float4* cand = (float4*)(ws + (5 << 20));  // 4 MB   (8 x 32768 x 16 B)
  int* out = (int*)d_out;

  proj_prep_kernel<<<512 + N_BOOKS / 256, 256, 0, stream>>>(x, w, tsplit, codebook, bfrag,
                                                            nh_g, ctr);
  score_kernel<<<128 * SC_H, 256, 0, stream>>>(tsplit, bfrag, nh_g, cand);
  merge_flag_kernel<<<N_ROWS / 256, 256, 0, stream>>>(cand, out, list, ctr);
  rescore_kernel<<<512, 256, 0, stream>>>(list, ctr, x, w, codebook, out);
}

// Round 13
// 172.451 us; speedup vs baseline: 1.1173x; 1.1173x over previous
//
#include <hip/hip_runtime.h>

#define N_ROWS 32768
#define D_IN 320
#define CB 16
#define N_BOOKS 8192

typedef __attribute__((ext_vector_type(8))) short bf16x8;
typedef __attribute__((ext_vector_type(4))) float f32x4;
#define MFMA __builtin_amdgcn_mfma_f32_16x16x32_bf16
#define AS1 __attribute__((address_space(1)))
#define AS3 __attribute__((address_space(3)))

__device__ __forceinline__ unsigned short bf16rn(float f) {
  unsigned u = __float_as_uint(f);
  u += 0x7fffu + ((u >> 16) & 1u);
  return (unsigned short)(u >> 16);
}
__device__ __forceinline__ float bf16tof(unsigned short h) {
  return __uint_as_float(((unsigned)h) << 16);
}
// async global->LDS, 16B per lane; lds ptr must be wave-uniform base
__device__ __forceinline__ void gload_lds16(const short* g, short* l) {
  __builtin_amdgcn_global_load_lds((const AS1 unsigned int*)g, (AS3 unsigned int*)l, 16, 0, 0);
}

// ---------------- Kernel 1 (fused): proj (blocks 0..511) + codebook prep (512..543) -------
// prep: 2-SPLIT bfrag[bt][split][lane][8]; B1=[c1|c1], B2=[c2|c2]; tile = 1024 shorts.
// nh = -0.5||c||^2 (fp64). Zeroes flagged-row counter.
// proj: targets = X @ W^T via bf16 3-split MFMA (3-split needed for t's VALUE precision),
// f32 chained accumulators. Epilogue stores only t1|t2 (R13: t3 storage was dead — score
// reads A12=[t1|t2] only, rescore recomputes from x in fp64). tsplit stride 32 shorts.
__global__ __launch_bounds__(256, 2) void proj_prep_kernel(
    const float* __restrict__ x, const float* __restrict__ w, short* __restrict__ tsplit,
    const float* __restrict__ cbk, short* __restrict__ bfrag, float* __restrict__ nh_g,
    int* __restrict__ ctr) {
  __shared__ __align__(16) short wfrag[3][10][64][8];  // 30720 B
  __shared__ __align__(16) float xs[2][64 * 36];       // 18432 B
  const int tid = threadIdx.x;

  if (blockIdx.x >= 512) {  // ---- prep branch (no LDS, no syncthreads) ----
    const int bid = blockIdx.x - 512;
    if (bid == 0 && tid == 0) *ctr = 0;
    const int j = bid * 256 + tid;
    const float4* src = (const float4*)(cbk + (size_t)j * CB);
    float4 a = src[0], b = src[1], c = src[2], d = src[3];
    float ce[16] = {a.x, a.y, a.z, a.w, b.x, b.y, b.z, b.w,
                    c.x, c.y, c.z, c.w, d.x, d.y, d.z, d.w};
    short c1[16], c2[16];
    double s = 0.0;
#pragma unroll
    for (int i = 0; i < 16; i++) {
      s += (double)ce[i] * (double)ce[i];
      unsigned short x1 = bf16rn(ce[i]);
      float r1 = ce[i] - bf16tof(x1);
      unsigned short x2 = bf16rn(r1);
      c1[i] = (short)x1; c2[i] = (short)x2;
    }
    nh_g[j] = (float)(-0.5 * s);
    bf16x8 lo1, hi1, lo2, hi2;
#pragma unroll
    for (int i = 0; i < 8; i++) {
      lo1[i] = c1[i]; hi1[i] = c1[i + 8];
      lo2[i] = c2[i]; hi2[i] = c2[i + 8];
    }
    const int bt = j >> 4, n = j & 15;
    short* base = bfrag + (size_t)bt * 1024;
    *(bf16x8*)(base + (0 * 16 + n) * 8) = lo1;
    *(bf16x8*)(base + (1 * 16 + n) * 8) = hi1;
    *(bf16x8*)(base + (2 * 16 + n) * 8) = lo1;
    *(bf16x8*)(base + (3 * 16 + n) * 8) = hi1;
    *(bf16x8*)(base + 512 + (0 * 16 + n) * 8) = lo2;
    *(bf16x8*)(base + 512 + (1 * 16 + n) * 8) = hi2;
    *(bf16x8*)(base + 512 + (2 * 16 + n) * 8) = lo2;
    *(bf16x8*)(base + 512 + (3 * 16 + n) * 8) = hi2;
    return;
  }

  // ---- proj branch ----
  const int lane = tid & 63;
  const int wv = tid >> 6;

  for (int i = tid; i < D_IN * CB; i += 256) {
    int d = i >> 4, o = i & 15;
    float f = w[o * D_IN + d];
    unsigned short h1 = bf16rn(f);
    float r1 = f - bf16tof(h1);
    unsigned short h2 = bf16rn(r1);
    float r2 = r1 - bf16tof(h2);
    unsigned short h3 = bf16rn(r2);
    int c = d >> 5, qq = (d >> 3) & 3, pos = d & 7;
    int ln = qq * 16 + o;
    wfrag[0][c][ln][pos] = (short)h1;
    wfrag[1][c][ln][pos] = (short)h2;
    wfrag[2][c][ln][pos] = (short)h3;
  }

  const float* xblk = x + (size_t)blockIdx.x * 64 * D_IN;
  {
    int row = tid >> 2, k0 = (tid & 3) * 8;
    float4 v0 = *(const float4*)(xblk + row * D_IN + k0);
    float4 v1 = *(const float4*)(xblk + row * D_IN + k0 + 4);
    *(float4*)&xs[0][row * 36 + k0] = v0;
    *(float4*)&xs[0][row * 36 + k0 + 4] = v1;
  }
  __syncthreads();

  const int m = lane & 15, q = lane >> 4;
  f32x4 g1 = {0.f, 0.f, 0.f, 0.f}, g2 = {0.f, 0.f, 0.f, 0.f}, g3 = {0.f, 0.f, 0.f, 0.f};
  for (int c = 0; c < 10; c++) {
    const int buf = c & 1;
    if (c < 9) {
      int row = tid >> 2, k0 = (tid & 3) * 8;
      float4 v0 = *(const float4*)(xblk + row * D_IN + (c + 1) * 32 + k0);
      float4 v1 = *(const float4*)(xblk + row * D_IN + (c + 1) * 32 + k0 + 4);
      *(float4*)&xs[buf ^ 1][row * 36 + k0] = v0;
      *(float4*)&xs[buf ^ 1][row * 36 + k0 + 4] = v1;
    }
    const float* xp = &xs[buf][(wv * 16 + m) * 36 + q * 8];
    float4 xa = *(const float4*)xp;
    float4 xb = *(const float4*)(xp + 4);
    float xe[8] = {xa.x, xa.y, xa.z, xa.w, xb.x, xb.y, xb.z, xb.w};
    bf16x8 a1, a2, a3;
#pragma unroll
    for (int j = 0; j < 8; j++) {
      unsigned short h1 = bf16rn(xe[j]);
      float r1 = xe[j] - bf16tof(h1);
      unsigned short h2 = bf16rn(r1);
      float r2 = r1 - bf16tof(h2);
      unsigned short h3 = bf16rn(r2);
      a1[j] = (short)h1; a2[j] = (short)h2; a3[j] = (short)h3;
    }
    bf16x8 b1 = *(const bf16x8*)wfrag[0][c][lane];
    bf16x8 b2 = *(const bf16x8*)wfrag[1][c][lane];
    bf16x8 b3 = *(const bf16x8*)wfrag[2][c][lane];
    g1 = MFMA(a1, b1, g1, 0, 0, 0);
    g2 = MFMA(a2, b1, g2, 0, 0, 0);
    g2 = MFMA(a1, b2, g2, 0, 0, 0);
    g3 = MFMA(a3, b1, g3, 0, 0, 0);
    g3 = MFMA(a1, b3, g3, 0, 0, 0);
    g3 = MFMA(a2, b2, g3, 0, 0, 0);
    __syncthreads();
  }

  float* tl = (float*)xs;  // 64 rows x stride 17
#pragma unroll
  for (int r = 0; r < 4; r++) {
    double t = (double)g1[r] + ((double)g2[r] + (double)g3[r]);
    tl[(wv * 16 + q * 4 + r) * 17 + m] = (float)t;
  }
  __syncthreads();
  {
    int row_l = tid >> 2, p = tid & 3;
    short h1[4], h2[4];
#pragma unroll
    for (int i = 0; i < 4; i++) {
      float f = tl[row_l * 17 + p * 4 + i];
      unsigned short a = bf16rn(f);
      float r1 = f - bf16tof(a);
      unsigned short b = bf16rn(r1);
      h1[i] = (short)a; h2[i] = (short)b;
    }
    size_t base = (size_t)(blockIdx.x * 64 + row_l) * 32;
    *(short4*)(tsplit + base + p * 4) = make_short4(h1[0], h1[1], h1[2], h1[3]);
    *(short4*)(tsplit + base + 16 + p * 4) = make_short4(h2[0], h2[1], h2[2], h2[3]);
  }
}

// ---------------- Kernel 2: 3-buffer rotation + raw barrier + counted vmcnt (R10 best) ----
// Session-best score structure (R10, 175.7us total). 512-thr blocks, 2 rt/wave, shared
// 3-buf LDS rotation; raw s_barrier + counted s_waitcnt vmcnt(2): substage sc+1's loads
// stay in flight across the barrier. Buffer-reuse safety: wave issuing into buf[(sc+1)%3]
// passed barrier(sc-1) => all waves done compute(sc-2) which read that buffer.
// Index-in-mantissa top-2 (R8): score quantized to 26-bit prefix, low 6 bits = tag(63-bt);
// fmax propagates identity free; recovery via ballot+tag. Quant error <=2.4e-4; any
// ambiguity -> s1-s2 < eps -> flagged -> fp64 rescore (rescue-netted).
#define SC_H 8

__global__ __launch_bounds__(512, 2) void score_kernel(const short* __restrict__ tsplit,
                                                       const short* __restrict__ bfrag,
                                                       const float* __restrict__ nh_g,
                                                       float4* __restrict__ cand) {
  __shared__ __align__(16) short ldsb[3][8192];  // 3 bufs x 16 KB = 48 KB
  __shared__ float ldsnh[1024];                  // 4 KB -> total 53,248 B
  const int tid = threadIdx.x;
  const int lane = tid & 63;
  const int wv = tid >> 6;  // 0..7
  const int m = lane & 15, q = lane >> 4;
  const int rb = blockIdx.x & 127;
  const int h = blockIdx.x >> 7;  // 0..7
  const int rowbase = rb * 256;

  // A-frags from prepacked tsplit: A12 = [t1|t2]; wave covers rows wv*32 .. wv*32+31
  bf16x8 A12[2];
#pragma unroll
  for (int rt = 0; rt < 2; rt++) {
    int row = rowbase + wv * 32 + rt * 16 + m;
    A12[rt] = *(const bf16x8*)(tsplit + (size_t)row * 32 + q * 8);
  }
  for (int i = tid; i < 1024; i += 512) ldsnh[i] = nh_g[h * 1024 + i];

  // wave wv stages shorts [wv*1024, wv*1024+1024) of each 8-tile (16 KB) substage
  const short* gw = bfrag + (size_t)h * 65536 + wv * 1024 + lane * 8;
  // prologue: stage substage 0 into buf 0
  gload_lds16(gw, &ldsb[0][wv * 1024]);
  gload_lds16(gw + 512, &ldsb[0][wv * 1024 + 512]);

  const unsigned qmask = 0xFFFFFFC0u;
  float s1[2][4], s2[2][4];
#pragma unroll
  for (int rt = 0; rt < 2; rt++)
#pragma unroll
    for (int r = 0; r < 4; r++) { s1[rt][r] = -3.4e38f; s2[rt][r] = -3.4e38f; }

  __syncthreads();  // full drain once: nh + substage-0 visible to all waves

  for (int sc = 0; sc < 8; sc++) {
    if (sc < 7) {  // stage next substage; its 2 loads stay in flight across the barrier
      const short* gs = gw + (sc + 1) * 8192;
      short* ld = &ldsb[(sc + 1) % 3][wv * 1024];
      gload_lds16(gs, ld);
      gload_lds16(gs + 512, ld + 512);
      asm volatile("s_waitcnt vmcnt(2)" ::: "memory");  // my substage-sc loads done
    } else {
      asm volatile("s_waitcnt vmcnt(0)" ::: "memory");
    }
    __builtin_amdgcn_s_barrier();       // all waves' substage-sc writes now in LDS
    asm volatile("" ::: "memory");      // fence: no LDS reads hoisted above the barrier
    const short* bufp = &ldsb[sc % 3][0];
#pragma unroll
    for (int bt = 0; bt < 8; bt++) {
      const short* bp = bufp + bt * 1024;
      bf16x8 b1 = *(const bf16x8*)(bp + lane * 8);
      bf16x8 b2 = *(const bf16x8*)(bp + 512 + lane * 8);
      const int btg = sc * 8 + bt;
      float nh0 = ldsnh[btg * 16 + m];
      f32x4 ci = {nh0, nh0, nh0, nh0};
      const unsigned tagv = (unsigned)(63 - btg);  // prefer low bt on quantized ties
#pragma unroll
      for (int rt = 0; rt < 2; rt++) {
        f32x4 acc = MFMA(A12[rt], b1, ci, 0, 0, 0);
        acc = MFMA(A12[rt], b2, acc, 0, 0, 0);
#pragma unroll
        for (int r = 0; r < 4; r++) {
          float vq = __uint_as_float((__float_as_uint(acc[r]) & qmask) | tagv);
          s2[rt][r] = __builtin_amdgcn_fmed3f(vq, s1[rt][r], s2[rt][r]);
          s1[rt][r] = fmaxf(s1[rt][r], vq);
        }
      }
    }
  }

  // cross-lane top-2 merge over 16 column-lanes; index recovered from tag + ballot
#pragma unroll
  for (int rt = 0; rt < 2; rt++)
#pragma unroll
    for (int r = 0; r < 4; r++) {
      float s1v = s1[rt][r], s2v = s2[rt][r];
      const float ps1 = s1v;  // pre-merge value: identifies the owner lane
#pragma unroll
      for (int msk = 1; msk <= 8; msk <<= 1) {
        float o1 = __shfl_xor(s1v, msk);
        float o2 = __shfl_xor(s2v, msk);
        s2v = __builtin_amdgcn_fmed3f(s1v, o1, fmaxf(s2v, o2));
        s1v = fmaxf(s1v, o1);
      }
      unsigned long long bal = __ballot(ps1 == s1v);
      unsigned grp = (unsigned)((bal >> (q * 16)) & 0xFFFFull);
      int mwin = __builtin_ctz(grp | 0x10000u);  // grp!=0 guaranteed; | is safety
      int btwin = 63 - (int)(__float_as_uint(s1v) & 63u);
      int col = h * 1024 + btwin * 16 + mwin;
      if (m == 0) {
        int row = rowbase + wv * 32 + rt * 16 + q * 4 + r;
        cand[(size_t)h * N_ROWS + row] = make_float4(s1v, s2v, __int_as_float(col), 0.f);
      }
    }
}

// ---------------- Kernel 3a: merge eighths, flag near-ties into compacted list ------------
// eps 1e-3 covers: 2-split error (~2e-4) + mantissa quantization (<=2.4e-4).
#define MARGIN_EPS 1.0e-3f

__global__ __launch_bounds__(256) void merge_flag_kernel(const float4* __restrict__ cand,
                                                         int* __restrict__ out,
                                                         int* __restrict__ list,
                                                         int* __restrict__ ctr) {
  const int r = blockIdx.x * 256 + threadIdx.x;
  float S1 = -3.4e38f, S2 = -3.4e38f;
  int I = 0;
#pragma unroll
  for (int h = 0; h < SC_H; h++) {  // ascending + strict '>' => min index on ties
    float4 v = cand[(size_t)h * N_ROWS + r];
    if (v.x > S1) {
      S2 = fmaxf(S1, v.y); S1 = v.x; I = __float_as_int(v.z);
    } else {
      S2 = fmaxf(S2, v.x);
    }
  }
  out[r] = I;
  if (S1 - S2 < MARGIN_EPS) {
    int slot = atomicAdd(ctr, 1);  // device-scope by default: safe across XCDs
    list[slot] = r;
  }
}

// ---------------- Kernel 3b: exact fp64 rescore, one block per flagged row ----------------
__global__ __launch_bounds__(256) void rescore_kernel(const int* __restrict__ list,
                                                      const int* __restrict__ ctr,
                                                      const float* __restrict__ x,
                                                      const float* __restrict__ w,
                                                      const float* __restrict__ codebook,
                                                      int* __restrict__ out) {
  __shared__ double ps[16][17];
  __shared__ double tsh[16];
  __shared__ double rs[256];
  __shared__ int ri[256];
  const int tid = threadIdx.x;
  const int total = ctr[0];

  for (int it = blockIdx.x; it < total; it += gridDim.x) {
    const int row = list[it];
    {  // exact fp64 t = x_row . W^T
      int o = tid & 15, c = tid >> 4;
      double p = 0.0;
      for (int k = 0; k < 20; k++) {
        int d = c * 20 + k;
        p = fma((double)x[(size_t)row * D_IN + d], (double)w[o * D_IN + d], p);
      }
      ps[c][o] = p;
    }
    __syncthreads();
    if (tid < 16) {
      double t = 0.0;
      for (int c = 0; c < 16; c++) t += ps[c][tid];
      tsh[tid] = t;
    }
    __syncthreads();
    double t[16];
#pragma unroll
    for (int i = 0; i < 16; i++) t[i] = tsh[i];
    double bs = -1.0e300;
    int bi = 0;
    for (int j = tid; j < N_BOOKS; j += 256) {
      const float* cp = codebook + (size_t)j * CB;
      double dot = 0.0, cc = 0.0;
#pragma unroll
      for (int i = 0; i < 16; i++) {
        double cv = (double)cp[i];
        dot = fma(t[i], cv, dot);
        cc = fma(cv, cv, cc);
      }
      double mv = dot - 0.5 * cc;
      if (mv > bs) { bs = mv; bi = j; }  // ascending j: first wins
    }
    rs[tid] = bs; ri[tid] = bi;
    __syncthreads();
    for (int s = 128; s > 0; s >>= 1) {
      if (tid < s) {
        double os = rs[tid + s]; int oi = ri[tid + s];
        if (os > rs[tid] || (os == rs[tid] && oi < ri[tid])) { rs[tid] = os; ri[tid] = oi; }
      }
      __syncthreads();
    }
    if (tid == 0) out[row] = ri[0];
    __syncthreads();  // protect ps/rs reuse on next list item
  }
}

extern "C" void kernel_launch(void* const* d_in, const int* in_sizes, int n_in,
                              void* d_out, int out_size, void* d_ws, size_t ws_size,
                              hipStream_t stream) {
  (void)in_sizes; (void)n_in; (void)out_size; (void)ws_size;
  const float* x = (const float*)d_in[0];
  // d_in[1] = mask_time_indices: all-ones -> flatten; unused
  const float* w = (const float*)d_in[2];
  const float* codebook = (const float*)d_in[3];

  char* ws = (char*)d_ws;
  short* tsplit = (short*)(ws);              // 2 MB   (32768 x 32 shorts)
  short* bfrag = (short*)(ws + (2 << 20));   // 1 MB   (512 bt x 1024 shorts)
  float* nh_g = (float*)(ws + (3 << 20));    // 32 KB
  int* list = (int*)(ws + 3182592);          // 128 KB flagged-row list (4KB pad before)
  int* ctr = (int*)(ws + 3313664);           // 4 B    flagged-row count
  float4* cand = (float4*)(ws + (4 << 20));  // 4 MB   (8 x 32768 x 16 B)
  int* out = (int*)d_out;

  proj_prep_kernel<<<512 + N_BOOKS / 256, 256, 0, stream>>>(x, w, tsplit, codebook, bfrag,
                                                            nh_g, ctr);
  score_kernel<<<128 * SC_H, 512, 0, stream>>>(tsplit, bfrag, nh_g, cand);
  merge_flag_kernel<<<N_ROWS / 256, 256, 0, stream>>>(cand, out, list, ctr);
  rescore_kernel<<<512, 256, 0, stream>>>(list, ctr, x, w, codebook, out);
}